// Round 1
// baseline (1116.264 us; speedup 1.0000x reference)
//
#include <hip/hip_runtime.h>
#include <math.h>

typedef unsigned short ushort_t;
typedef __attribute__((ext_vector_type(8))) short short8;
typedef __attribute__((ext_vector_type(4))) float f32x4;

#define LDA 264
#define B_TOTAL 131072

// ws layout: bf16 (ushort) region first, then fp32 region at byte 860160
#define OFF_VIB 0
#define OFF_ACO 12288
#define OFF_TMP 61440
#define OFF_FUS 86016
#define OFF_WQ 196608
#define OFF_WO 307200
#define OFF_GRID 417792
#define F32_BYTE_OFF 860160
#define F_KB 0
#define F_VB 9216
#define F_GGN 18432
#define F_CNT 18496

__device__ __forceinline__ ushort_t f2bu(float f) {
  union { float f; unsigned u; } c; c.f = f;
  unsigned u = c.u;
  unsigned r = (u + 0x7fffu + ((u >> 16) & 1u)) >> 16;  // RTNE
  return (ushort_t)r;
}
__device__ __forceinline__ float bu2f(ushort_t b) {
  union { unsigned u; float f; } c; c.u = ((unsigned)b) << 16; return c.f;
}
__device__ __forceinline__ float gelu_exact(float x) {
  return 0.5f * x * (1.0f + erff(x * 0.70710678118654752440f));
}

// ---------------- prep: weights -> bf16 transposed WT[n][k] ----------------
__global__ void prep_weights(const float* __restrict__ ev, const float* __restrict__ ea,
                             const float* __restrict__ et, const float* __restrict__ fw,
                             const float* __restrict__ rwq, const float* __restrict__ rwo,
                             const float* __restrict__ gr, ushort_t* __restrict__ ws) {
  int tid = blockIdx.x * blockDim.x + threadIdx.x;
  int nth = gridDim.x * blockDim.x;
  for (int i = tid; i < 12288; i += nth) { int n = i >> 6, k = i & 63;  ws[OFF_VIB + i] = f2bu(ev[k * 192 + n]); }
  for (int i = tid; i < 49152; i += nth) { int n = i >> 8, k = i & 255; ws[OFF_ACO + i] = f2bu(ea[k * 192 + n]); }
  for (int i = tid; i < 24576; i += nth) { int n = i >> 7, k = i & 127; ws[OFF_TMP + i] = f2bu(et[k * 192 + n]); }
  for (int i = tid; i < 110592; i += nth) {
    int c = i / 36864, r = i % 36864; int n = r / 192, k = r % 192;
    ws[OFF_FUS + i] = f2bu(fw[(c * 192 + k) * 192 + n]);
  }
  for (int i = tid; i < 110592; i += nth) {
    int l = i / 36864, r = i % 36864; int n = r / 192, k = r % 192;
    ws[OFF_WQ + i] = f2bu(rwq[l * 36864 + k * 192 + n]);
  }
  for (int i = tid; i < 110592; i += nth) {
    int l = i / 36864, r = i % 36864; int n = r / 192, k = r % 192;
    ws[OFF_WO + i] = f2bu(rwo[l * 36864 + k * 192 + n]);
  }
  for (int i = tid; i < 12288; i += nth) { ws[OFF_GRID + i] = f2bu(gr[i]); }
}

// ---------------- prep: K/V banks (fp32), grid norms, zero counts ----------
__global__ void prep_kv(const float* __restrict__ rwk, const float* __restrict__ rwv,
                        const float* __restrict__ rbk, const float* __restrict__ rbv,
                        const float* __restrict__ rmem, const float* __restrict__ gr,
                        float* __restrict__ kb, float* __restrict__ vb,
                        float* __restrict__ ggn, unsigned* __restrict__ cnt) {
  int tid = blockIdx.x * blockDim.x + threadIdx.x;
  int nth = gridDim.x * blockDim.x;
  for (int idx = tid; idx < 18432; idx += nth) {
    int bank = idx / 9216, r = idx % 9216;
    int i = r / 3072, s2 = r % 3072, slot = s2 / 192, d = s2 % 192;
    const float* w  = (bank ? rwv : rwk) + i * 36864;
    const float* bs = (bank ? rbv : rbk) + i * 192;
    const float* mm = rmem + i * 3072 + slot * 192;
    float acc = bs[d];
    for (int k = 0; k < 192; ++k) acc += mm[k] * w[k * 192 + d];
    (bank ? vb : kb)[r] = acc;
  }
  for (int g = tid; g < 64; g += nth) {
    const float* gp = gr + g * 192;
    float s = 0.f;
    for (int k = 0; k < 192; ++k) s += gp[k] * gp[k];
    ggn[g] = s;
    cnt[g] = 0u;
  }
}

// ---------------- main kernel helpers ----------------
template<int NT, int KIT>
__device__ __forceinline__ void mma_nt(const ushort_t* Awave, int akoff,
                                       const ushort_t* W, int ldw, int lane, f32x4* acc) {
  const int m = lane & 15, gq = lane >> 4;
#pragma unroll
  for (int kk = 0; kk < KIT; ++kk) {
    short8 a = *(const short8*)(Awave + m * LDA + akoff + kk * 32 + gq * 8);
#pragma unroll
    for (int t = 0; t < NT; ++t) {
      short8 b = *(const short8*)(W + (t * 16 + m) * ldw + kk * 32 + gq * 8);
      acc[t] = __builtin_amdgcn_mfma_f32_16x16x32_bf16(a, b, acc[t], 0, 0, 0);
    }
  }
}

template<int K>
__device__ __forceinline__ void stage_x(const float* __restrict__ x, int grow0,
                                        ushort_t* __restrict__ Ab, int tid) {
  constexpr int C4 = K / 4;
  for (int idx = tid; idx < 64 * C4; idx += 256) {
    int r = idx / C4, c = idx % C4;
    float4 v = *(const float4*)(x + (size_t)(grow0 + r) * K + c * 4);
    ushort_t t4[4] = { f2bu(v.x), f2bu(v.y), f2bu(v.z), f2bu(v.w) };
    *(uint2*)(Ab + r * LDA + c * 4) = *(uint2*)t4;
  }
}

__device__ __forceinline__ void stage_w(const ushort_t* __restrict__ wt, int Kfull, int k0, int KC,
                                        int rows, int ldw, ushort_t* __restrict__ Wb, int tid) {
  int per = KC >> 3;
  int tot = rows * per;
  for (int idx = tid; idx < tot; idx += 256) {
    int r = idx / per, c = idx % per;
    short8 v = *(const short8*)(wt + (size_t)r * Kfull + k0 + c * 8);
    *(short8*)(Wb + r * ldw + c * 8) = v;
  }
}

__device__ __forceinline__ void stage_f(const float* __restrict__ src, float* __restrict__ dst, int tid) {
  for (int idx = tid; idx < 768; idx += 256)
    ((float4*)dst)[idx] = ((const float4*)src)[idx];
}

__device__ __forceinline__ void ln_gelu_store(f32x4* acc, const float* __restrict__ bias,
                                              const float* __restrict__ gam, const float* __restrict__ bet,
                                              ushort_t* __restrict__ Arow0, int lane) {
  const int c0 = lane & 15;
#pragma unroll
  for (int t = 0; t < 12; ++t) {
    float bv = bias[t * 16 + c0];
#pragma unroll
    for (int j = 0; j < 4; ++j) acc[t][j] += bv;
  }
  float mean[4], rstd[4];
#pragma unroll
  for (int j = 0; j < 4; ++j) {
    float s = 0.f;
#pragma unroll
    for (int t = 0; t < 12; ++t) s += acc[t][j];
#pragma unroll
    for (int off = 1; off < 16; off <<= 1) s += __shfl_xor(s, off, 64);
    mean[j] = s * (1.0f / 192.0f);
    float qv = 0.f;
#pragma unroll
    for (int t = 0; t < 12; ++t) { float d = acc[t][j] - mean[j]; qv += d * d; }
#pragma unroll
    for (int off = 1; off < 16; off <<= 1) qv += __shfl_xor(qv, off, 64);
    rstd[j] = rsqrtf(qv * (1.0f / 192.0f) + 1e-5f);
  }
#pragma unroll
  for (int t = 0; t < 12; ++t) {
    int col = t * 16 + c0;
    float ga = gam[col], be = bet[col];
#pragma unroll
    for (int j = 0; j < 4; ++j) {
      float y = (acc[t][j] - mean[j]) * rstd[j] * ga + be;
      Arow0[j * LDA + col] = f2bu(gelu_exact(y));
    }
  }
}

__device__ __forceinline__ void bias_store(f32x4* acc, const float* __restrict__ bias,
                                           ushort_t* __restrict__ Arow0, int lane) {
  const int c0 = lane & 15;
#pragma unroll
  for (int t = 0; t < 12; ++t) {
    int col = t * 16 + c0;
    float bv = bias[col];
#pragma unroll
    for (int j = 0; j < 4; ++j)
      Arow0[j * LDA + col] = f2bu(acc[t][j] + bv);
  }
}

__device__ __forceinline__ void attention(const float* __restrict__ Kl, const float* __restrict__ Vl,
                                          ushort_t* __restrict__ Ab, int tid) {
  const int r = tid >> 2, h = tid & 3;
  ushort_t* qp = Ab + r * LDA + h * 48;
  float q[48];
#pragma unroll
  for (int d8 = 0; d8 < 6; ++d8) {
    short8 v = *(const short8*)(qp + d8 * 8);
#pragma unroll
    for (int j = 0; j < 8; ++j) q[d8 * 8 + j] = bu2f((ushort_t)v[j]);
  }
  float sc[16];
#pragma unroll
  for (int m = 0; m < 16; ++m) {
    const float* kr = Kl + m * 192 + h * 48;
    float s = 0.f;
#pragma unroll
    for (int d4 = 0; d4 < 12; ++d4) {
      float4 kv = *(const float4*)(kr + d4 * 4);
      s += q[d4 * 4 + 0] * kv.x + q[d4 * 4 + 1] * kv.y + q[d4 * 4 + 2] * kv.z + q[d4 * 4 + 3] * kv.w;
    }
    sc[m] = s * 0.144337567297406441f;  // 1/sqrt(48)
  }
  float mx = sc[0];
#pragma unroll
  for (int m = 1; m < 16; ++m) mx = fmaxf(mx, sc[m]);
  float den = 0.f;
#pragma unroll
  for (int m = 0; m < 16; ++m) { sc[m] = expf(sc[m] - mx); den += sc[m]; }
  float inv = 1.f / den;
#pragma unroll
  for (int m = 0; m < 16; ++m) sc[m] *= inv;
  float o[48];
#pragma unroll
  for (int d = 0; d < 48; ++d) o[d] = 0.f;
#pragma unroll
  for (int m = 0; m < 16; ++m) {
    const float* vr = Vl + m * 192 + h * 48;
    float a = sc[m];
#pragma unroll
    for (int d4 = 0; d4 < 12; ++d4) {
      float4 vv = *(const float4*)(vr + d4 * 4);
      o[d4 * 4 + 0] += a * vv.x; o[d4 * 4 + 1] += a * vv.y;
      o[d4 * 4 + 2] += a * vv.z; o[d4 * 4 + 3] += a * vv.w;
    }
  }
#pragma unroll
  for (int d2 = 0; d2 < 24; ++d2) {
    ushort_t t2[2] = { f2bu(o[d2 * 2]), f2bu(o[d2 * 2 + 1]) };
    *(unsigned*)(qp + d2 * 2) = *(unsigned*)t2;
  }
}

__device__ __forceinline__ void sofm_ep(f32x4* acc, const float* __restrict__ c_l,
                                        unsigned* __restrict__ hist, int lane) {
  const int c0 = lane & 15;
#pragma unroll
  for (int j = 0; j < 4; ++j) {
    float bv = -3.0e38f; int bi = 0;
#pragma unroll
    for (int t = 0; t < 4; ++t) {
      int gi = t * 16 + c0;
      float v = acc[t][j] - c_l[gi];
      bool take = (v > bv);
      bv = take ? v : bv; bi = take ? gi : bi;
    }
#pragma unroll
    for (int off = 1; off < 16; off <<= 1) {
      float ov = __shfl_xor(bv, off, 64);
      int   oi = __shfl_xor(bi, off, 64);
      bool take = (ov > bv) || (ov == bv && oi < bi);
      bv = take ? ov : bv; bi = take ? oi : bi;
    }
    if (c0 == 0) atomicAdd(&hist[bi], 1u);
  }
}

// ---------------- main fused kernel ----------------
__global__ __launch_bounds__(256, 1) void arn_main(
    const float* __restrict__ xv, const float* __restrict__ xa, const float* __restrict__ xt,
    const ushort_t* __restrict__ wsu, const float* __restrict__ kb, const float* __restrict__ vbnk,
    const float* __restrict__ ggn, unsigned* __restrict__ counts,
    const float* __restrict__ ebv, const float* __restrict__ egv, const float* __restrict__ ebbv,
    const float* __restrict__ eba, const float* __restrict__ ega, const float* __restrict__ ebba,
    const float* __restrict__ ebt, const float* __restrict__ egt, const float* __restrict__ ebbt,
    const float* __restrict__ fb, const float* __restrict__ fg, const float* __restrict__ fbb,
    const float* __restrict__ rbq, const float* __restrict__ rbo) {
  __shared__ __align__(16) ushort_t Abuf[64 * LDA];   // 33,792 B
  __shared__ __align__(16) ushort_t Wbuf[192 * 200];  // 76,800 B
  __shared__ __align__(16) float Kl[16 * 192];        // 12,288 B
  __shared__ __align__(16) float Vl[16 * 192];        // 12,288 B
  __shared__ float c_l[64];
  __shared__ unsigned hist[64];

  const int tid = threadIdx.x;
  const int lane = tid & 63, wave = tid >> 6;
  const int grow0 = blockIdx.x * 64;
  const int gq = lane >> 4;
  ushort_t* Aw = Abuf + wave * 16 * LDA;                 // wave's 16-row A panel
  ushort_t* Arow0 = Abuf + (wave * 16 + 4 * gq) * LDA;   // epilogue row base (j adds rows)

  if (tid < 64) { hist[tid] = 0u; c_l[tid] = 0.5f * ggn[tid]; }

  f32x4 accF[12];
#pragma unroll
  for (int t = 0; t < 12; ++t) accF[t] = (f32x4){0.f, 0.f, 0.f, 0.f};

  // ---------- modality 0: vib (K=64) ----------
  stage_x<64>(xv, grow0, Abuf, tid);
  stage_w(wsu + OFF_VIB, 64, 0, 64, 192, 72, Wbuf, tid);
  __syncthreads();
  {
    f32x4 accE[12];
#pragma unroll
    for (int t = 0; t < 12; ++t) accE[t] = (f32x4){0.f, 0.f, 0.f, 0.f};
    mma_nt<12, 2>(Aw, 0, Wbuf, 72, lane, accE);
    ln_gelu_store(accE, ebv, egv, ebbv, Arow0, lane);
  }
  __syncthreads();
  stage_w(wsu + OFF_FUS + 0 * 36864, 192, 0, 192, 192, 200, Wbuf, tid);
  __syncthreads();
  mma_nt<12, 6>(Aw, 0, Wbuf, 200, lane, accF);
  __syncthreads();

  // ---------- modality 1: aco (K=256, W staged in two 128-chunks) ----------
  stage_x<256>(xa, grow0, Abuf, tid);
  stage_w(wsu + OFF_ACO, 256, 0, 128, 192, 136, Wbuf, tid);
  __syncthreads();
  {
    f32x4 accE[12];
#pragma unroll
    for (int t = 0; t < 12; ++t) accE[t] = (f32x4){0.f, 0.f, 0.f, 0.f};
    mma_nt<12, 4>(Aw, 0, Wbuf, 136, lane, accE);
    __syncthreads();
    stage_w(wsu + OFF_ACO, 256, 128, 128, 192, 136, Wbuf, tid);
    __syncthreads();
    mma_nt<12, 4>(Aw, 128, Wbuf, 136, lane, accE);
    ln_gelu_store(accE, eba, ega, ebba, Arow0, lane);
  }
  __syncthreads();
  stage_w(wsu + OFF_FUS + 1 * 36864, 192, 0, 192, 192, 200, Wbuf, tid);
  __syncthreads();
  mma_nt<12, 6>(Aw, 0, Wbuf, 200, lane, accF);
  __syncthreads();

  // ---------- modality 2: tmp (K=128) ----------
  stage_x<128>(xt, grow0, Abuf, tid);
  stage_w(wsu + OFF_TMP, 128, 0, 128, 192, 136, Wbuf, tid);
  __syncthreads();
  {
    f32x4 accE[12];
#pragma unroll
    for (int t = 0; t < 12; ++t) accE[t] = (f32x4){0.f, 0.f, 0.f, 0.f};
    mma_nt<12, 4>(Aw, 0, Wbuf, 136, lane, accE);
    ln_gelu_store(accE, ebt, egt, ebbt, Arow0, lane);
  }
  __syncthreads();
  stage_w(wsu + OFF_FUS + 2 * 36864, 192, 0, 192, 192, 200, Wbuf, tid);
  __syncthreads();
  mma_nt<12, 6>(Aw, 0, Wbuf, 200, lane, accF);
  // fusion epilogue: LN+GELU -> fused0 (own rows; accF fully accumulated)
  ln_gelu_store(accF, fb, fg, fbb, Arow0, lane);
  __syncthreads();

  // ---------- 3 resonance layers ----------
  for (int i = 0; i < 3; ++i) {
    stage_w(wsu + OFF_WQ + i * 36864, 192, 0, 192, 192, 200, Wbuf, tid);
    stage_f(kb + i * 3072, Kl, tid);
    stage_f(vbnk + i * 3072, Vl, tid);
    __syncthreads();
    {
      f32x4 accQ[12];
#pragma unroll
      for (int t = 0; t < 12; ++t) accQ[t] = (f32x4){0.f, 0.f, 0.f, 0.f};
      mma_nt<12, 6>(Aw, 0, Wbuf, 200, lane, accQ);
      bias_store(accQ, rbq + i * 192, Arow0, lane);
    }
    __syncthreads();
    attention(Kl, Vl, Abuf, tid);
    __syncthreads();
    stage_w(wsu + OFF_WO + i * 36864, 192, 0, 192, 192, 200, Wbuf, tid);
    __syncthreads();
    {
      f32x4 accO[12];
#pragma unroll
      for (int t = 0; t < 12; ++t) accO[t] = (f32x4){0.f, 0.f, 0.f, 0.f};
      mma_nt<12, 6>(Aw, 0, Wbuf, 200, lane, accO);
      bias_store(accO, rbo + i * 192, Arow0, lane);
    }
    __syncthreads();
  }

  // ---------- SOFM: argmax_g (f.g - ||g||^2/2) -> histogram ----------
  stage_w(wsu + OFF_GRID, 192, 0, 192, 64, 200, Wbuf, tid);
  __syncthreads();
  {
    f32x4 accS[4];
#pragma unroll
    for (int t = 0; t < 4; ++t) accS[t] = (f32x4){0.f, 0.f, 0.f, 0.f};
    mma_nt<4, 6>(Aw, 0, Wbuf, 200, lane, accS);
    sofm_ep(accS, c_l, hist, lane);
  }
  __syncthreads();
  if (tid < 64 && hist[tid]) atomicAdd(&counts[tid], hist[tid]);
}

// ---------------- finisher ----------------
__global__ void arn_finish(const unsigned* __restrict__ counts, const float* __restrict__ gr,
                           const float* __restrict__ ow, const float* __restrict__ ob,
                           float* __restrict__ out) {
  __shared__ float pooled[192];
  __shared__ float cf[64];
  int t = threadIdx.x;
  if (t < 64) cf[t] = (float)counts[t];
  __syncthreads();
  float s = 0.f;
  for (int g = 0; g < 64; ++g) s += cf[g] * gr[g * 192 + t];
  pooled[t] = s * (1.0f / (float)B_TOTAL);
  __syncthreads();
  if (t < 6) {
    float o = ob[t];
    for (int j = 0; j < 192; ++j) o += pooled[j] * ow[j * 6 + t];
    out[t] = (t == 1) ? fmaxf(o, 0.f) : 1.f / (1.f + expf(-o));
  }
}

// ---------------- launch ----------------
extern "C" void kernel_launch(void* const* d_in, const int* in_sizes, int n_in,
                              void* d_out, int out_size, void* d_ws, size_t ws_size,
                              hipStream_t stream) {
  (void)in_sizes; (void)n_in; (void)out_size; (void)ws_size;
  const float* xv   = (const float*)d_in[0];
  const float* xa   = (const float*)d_in[1];
  const float* xt   = (const float*)d_in[2];
  const float* ewv  = (const float*)d_in[3];
  const float* ebv  = (const float*)d_in[4];
  const float* egv  = (const float*)d_in[5];
  const float* ebbv = (const float*)d_in[6];
  const float* ewa  = (const float*)d_in[7];
  const float* eba  = (const float*)d_in[8];
  const float* ega  = (const float*)d_in[9];
  const float* ebba = (const float*)d_in[10];
  const float* ewt  = (const float*)d_in[11];
  const float* ebt  = (const float*)d_in[12];
  const float* egt  = (const float*)d_in[13];
  const float* ebbt = (const float*)d_in[14];
  const float* fw   = (const float*)d_in[15];
  const float* fb   = (const float*)d_in[16];
  const float* fg   = (const float*)d_in[17];
  const float* fbb  = (const float*)d_in[18];
  const float* rwq  = (const float*)d_in[19];
  const float* rwk  = (const float*)d_in[20];
  const float* rwv  = (const float*)d_in[21];
  const float* rwo  = (const float*)d_in[22];
  const float* rbq  = (const float*)d_in[23];
  const float* rbk  = (const float*)d_in[24];
  const float* rbv  = (const float*)d_in[25];
  const float* rbo  = (const float*)d_in[26];
  const float* rmem = (const float*)d_in[27];
  const float* grid = (const float*)d_in[28];
  const float* ow   = (const float*)d_in[29];
  const float* ob   = (const float*)d_in[30];

  ushort_t* wsu = (ushort_t*)d_ws;
  float* wsf = (float*)((char*)d_ws + F32_BYTE_OFF);
  float* kbank = wsf + F_KB;
  float* vbank = wsf + F_VB;
  float* ggn   = wsf + F_GGN;
  unsigned* cnt = (unsigned*)(wsf + F_CNT);

  prep_weights<<<dim3(256), dim3(256), 0, stream>>>(ewv, ewa, ewt, fw, rwq, rwo, grid, wsu);
  prep_kv<<<dim3(80), dim3(256), 0, stream>>>(rwk, rwv, rbk, rbv, rmem, grid, kbank, vbank, ggn, cnt);
  arn_main<<<dim3(2048), dim3(256), 0, stream>>>(xv, xa, xt, wsu, kbank, vbank, ggn, cnt,
      ebv, egv, ebbv, eba, ega, ebba, ebt, egt, ebbt, fb, fg, fbb, rbq, rbo);
  arn_finish<<<dim3(1), dim3(192), 0, stream>>>(cnt, grid, ow, ob, (float*)d_out);
}

// Round 2
// 537.101 us; speedup vs baseline: 2.0783x; 2.0783x over previous
//
#include <hip/hip_runtime.h>
#include <math.h>

typedef unsigned short ushort_t;
typedef __attribute__((ext_vector_type(8))) short short8;
typedef __attribute__((ext_vector_type(4))) float f32x4;

#define LDA 200
#define B_TOTAL 131072

// ws layout: bf16 (ushort) region first, then fp32 region at byte 860160
#define OFF_VIB 0
#define OFF_ACO 12288
#define OFF_TMP 61440
#define OFF_FUS 86016
#define OFF_WQ 196608
#define OFF_WO 307200
#define OFF_GRID 417792
#define F32_BYTE_OFF 860160
#define F_KB 0
#define F_VB 9216
#define F_GGN 18432
#define F_CNT 18496

__device__ __forceinline__ ushort_t f2bu(float f) {
  union { float f; unsigned u; } c; c.f = f;
  unsigned u = c.u;
  unsigned r = (u + 0x7fffu + ((u >> 16) & 1u)) >> 16;  // RTNE
  return (ushort_t)r;
}
__device__ __forceinline__ float bu2f(ushort_t b) {
  union { unsigned u; float f; } c; c.u = ((unsigned)b) << 16; return c.f;
}
__device__ __forceinline__ float gelu_exact(float x) {
  return 0.5f * x * (1.0f + erff(x * 0.70710678118654752440f));
}

// ---------------- prep: weights -> bf16 transposed WT[n][k] ----------------
__global__ void prep_weights(const float* __restrict__ ev, const float* __restrict__ ea,
                             const float* __restrict__ et, const float* __restrict__ fw,
                             const float* __restrict__ rwq, const float* __restrict__ rwo,
                             const float* __restrict__ gr, ushort_t* __restrict__ ws) {
  int tid = blockIdx.x * blockDim.x + threadIdx.x;
  int nth = gridDim.x * blockDim.x;
  for (int i = tid; i < 12288; i += nth) { int n = i >> 6, k = i & 63;  ws[OFF_VIB + i] = f2bu(ev[k * 192 + n]); }
  for (int i = tid; i < 49152; i += nth) { int n = i >> 8, k = i & 255; ws[OFF_ACO + i] = f2bu(ea[k * 192 + n]); }
  for (int i = tid; i < 24576; i += nth) { int n = i >> 7, k = i & 127; ws[OFF_TMP + i] = f2bu(et[k * 192 + n]); }
  for (int i = tid; i < 110592; i += nth) {
    int c = i / 36864, r = i % 36864; int n = r / 192, k = r % 192;
    ws[OFF_FUS + i] = f2bu(fw[(c * 192 + k) * 192 + n]);
  }
  for (int i = tid; i < 110592; i += nth) {
    int l = i / 36864, r = i % 36864; int n = r / 192, k = r % 192;
    ws[OFF_WQ + i] = f2bu(rwq[l * 36864 + k * 192 + n]);
  }
  for (int i = tid; i < 110592; i += nth) {
    int l = i / 36864, r = i % 36864; int n = r / 192, k = r % 192;
    ws[OFF_WO + i] = f2bu(rwo[l * 36864 + k * 192 + n]);
  }
  for (int i = tid; i < 12288; i += nth) { ws[OFF_GRID + i] = f2bu(gr[i]); }
}

// ---------------- prep: K/V banks (fp32), grid norms, zero counts ----------
__global__ void prep_kv(const float* __restrict__ rwk, const float* __restrict__ rwv,
                        const float* __restrict__ rbk, const float* __restrict__ rbv,
                        const float* __restrict__ rmem, const float* __restrict__ gr,
                        float* __restrict__ kb, float* __restrict__ vb,
                        float* __restrict__ ggn, unsigned* __restrict__ cnt) {
  int tid = blockIdx.x * blockDim.x + threadIdx.x;
  int nth = gridDim.x * blockDim.x;
  for (int idx = tid; idx < 18432; idx += nth) {
    int bank = idx / 9216, r = idx % 9216;
    int i = r / 3072, s2 = r % 3072, slot = s2 / 192, d = s2 % 192;
    const float* w  = (bank ? rwv : rwk) + i * 36864;
    const float* bs = (bank ? rbv : rbk) + i * 192;
    const float* mm = rmem + i * 3072 + slot * 192;
    float acc = bs[d];
    for (int k = 0; k < 192; ++k) acc += mm[k] * w[k * 192 + d];
    (bank ? vb : kb)[r] = acc;
  }
  for (int g = tid; g < 64; g += nth) {
    const float* gp = gr + g * 192;
    float s = 0.f;
    for (int k = 0; k < 192; ++k) s += gp[k] * gp[k];
    ggn[g] = s;
    cnt[g] = 0u;
  }
}

// ---------------- main kernel helpers ----------------
// A-fragment direct from global fp32 (lane m = row, gq selects k-subchunk)
template<int KIT>
__device__ __forceinline__ void load_afrag(const float* __restrict__ x, int row, int lane, short8* af) {
  const int gq = lane >> 4;
  const float* p = x + (size_t)row * (KIT * 32) + gq * 8;
#pragma unroll
  for (int kk = 0; kk < KIT; ++kk) {
    float4 a = *(const float4*)(p + kk * 32);
    float4 b = *(const float4*)(p + kk * 32 + 4);
    short8 v;
    v[0] = (short)f2bu(a.x); v[1] = (short)f2bu(a.y); v[2] = (short)f2bu(a.z); v[3] = (short)f2bu(a.w);
    v[4] = (short)f2bu(b.x); v[5] = (short)f2bu(b.y); v[6] = (short)f2bu(b.z); v[7] = (short)f2bu(b.w);
    af[kk] = v;
  }
}

// MFMA with A from registers, B (64 n-rows chunk) from LDS
template<int NT, int KIT>
__device__ __forceinline__ void mma_reg(const short8* af, const ushort_t* W, int ldw, int lane, f32x4* acc) {
  const int m = lane & 15, gq = lane >> 4;
#pragma unroll
  for (int kk = 0; kk < KIT; ++kk) {
#pragma unroll
    for (int t = 0; t < NT; ++t) {
      short8 b = *(const short8*)(W + (t * 16 + m) * ldw + kk * 32 + gq * 8);
      acc[t] = __builtin_amdgcn_mfma_f32_16x16x32_bf16(af[kk], b, acc[t], 0, 0, 0);
    }
  }
}

// MFMA with A (wave's 16 LDS rows) and B chunk from LDS
template<int NT, int KIT>
__device__ __forceinline__ void mma_lds(const ushort_t* Aw, const ushort_t* W, int ldw, int lane, f32x4* acc) {
  const int m = lane & 15, gq = lane >> 4;
#pragma unroll
  for (int kk = 0; kk < KIT; ++kk) {
    short8 a = *(const short8*)(Aw + m * LDA + kk * 32 + gq * 8);
#pragma unroll
    for (int t = 0; t < NT; ++t) {
      short8 b = *(const short8*)(W + (t * 16 + m) * ldw + kk * 32 + gq * 8);
      acc[t] = __builtin_amdgcn_mfma_f32_16x16x32_bf16(a, b, acc[t], 0, 0, 0);
    }
  }
}

// stage 64 n-rows x KC k-cols of WT[n][Kfull] into Wbuf[64][ldw]
__device__ __forceinline__ void stage_w(const ushort_t* __restrict__ wt, int Kfull, int k0, int KC,
                                        int r0, int ldw, ushort_t* __restrict__ Wb, int tid) {
  const int per = KC >> 3;
  const int tot = per << 6;
  for (int idx = tid; idx < tot; idx += 256) {
    int r = idx / per, c = idx - r * per;
    short8 v = *(const short8*)(wt + (size_t)(r0 + r) * Kfull + k0 + c * 8);
    *(short8*)(Wb + r * ldw + c * 8) = v;
  }
}

__device__ __forceinline__ void stage_kv(const float* __restrict__ kb, const float* __restrict__ vb,
                                         float* __restrict__ dst, int tid) {
  for (int idx = tid; idx < 768; idx += 256) {
    ((float4*)dst)[idx] = ((const float4*)kb)[idx];
    ((float4*)dst)[768 + idx] = ((const float4*)vb)[idx];
  }
}

__device__ __forceinline__ void ln_gelu_store(f32x4* acc, const float* __restrict__ bias,
                                              const float* __restrict__ gam, const float* __restrict__ bet,
                                              ushort_t* __restrict__ Arow0, int lane) {
  const int c0 = lane & 15;
#pragma unroll
  for (int t = 0; t < 12; ++t) {
    float bv = bias[t * 16 + c0];
#pragma unroll
    for (int j = 0; j < 4; ++j) acc[t][j] += bv;
  }
  float mean[4], rstd[4];
#pragma unroll
  for (int j = 0; j < 4; ++j) {
    float s = 0.f;
#pragma unroll
    for (int t = 0; t < 12; ++t) s += acc[t][j];
#pragma unroll
    for (int off = 1; off < 16; off <<= 1) s += __shfl_xor(s, off, 64);
    mean[j] = s * (1.0f / 192.0f);
    float qv = 0.f;
#pragma unroll
    for (int t = 0; t < 12; ++t) { float d = acc[t][j] - mean[j]; qv += d * d; }
#pragma unroll
    for (int off = 1; off < 16; off <<= 1) qv += __shfl_xor(qv, off, 64);
    rstd[j] = rsqrtf(qv * (1.0f / 192.0f) + 1e-5f);
  }
#pragma unroll
  for (int t = 0; t < 12; ++t) {
    int col = t * 16 + c0;
    float ga = gam[col], be = bet[col];
#pragma unroll
    for (int j = 0; j < 4; ++j) {
      float y = (acc[t][j] - mean[j]) * rstd[j] * ga + be;
      Arow0[j * LDA + col] = f2bu(gelu_exact(y));
    }
  }
}

__device__ __forceinline__ void bias_store(f32x4* acc, const float* __restrict__ bias,
                                           ushort_t* __restrict__ Arow0, int lane) {
  const int c0 = lane & 15;
#pragma unroll
  for (int t = 0; t < 12; ++t) {
    int col = t * 16 + c0;
    float bv = bias[col];
#pragma unroll
    for (int j = 0; j < 4; ++j)
      Arow0[j * LDA + col] = f2bu(acc[t][j] + bv);
  }
}

__device__ __forceinline__ void attention(const float* __restrict__ Kl, const float* __restrict__ Vl,
                                          ushort_t* __restrict__ Ab, int tid) {
  const int r = tid >> 2, h = tid & 3;
  ushort_t* qp = Ab + r * LDA + h * 48;
  float q[48];
#pragma unroll
  for (int d8 = 0; d8 < 6; ++d8) {
    short8 v = *(const short8*)(qp + d8 * 8);
#pragma unroll
    for (int j = 0; j < 8; ++j) q[d8 * 8 + j] = bu2f((ushort_t)v[j]);
  }
  float sc[16];
#pragma unroll
  for (int m = 0; m < 16; ++m) {
    const float* kr = Kl + m * 192 + h * 48;
    float s = 0.f;
#pragma unroll
    for (int d4 = 0; d4 < 12; ++d4) {
      float4 kv = *(const float4*)(kr + d4 * 4);
      s += q[d4 * 4 + 0] * kv.x + q[d4 * 4 + 1] * kv.y + q[d4 * 4 + 2] * kv.z + q[d4 * 4 + 3] * kv.w;
    }
    sc[m] = s * 0.144337567297406441f;  // 1/sqrt(48)
  }
  float mx = sc[0];
#pragma unroll
  for (int m = 1; m < 16; ++m) mx = fmaxf(mx, sc[m]);
  float den = 0.f;
#pragma unroll
  for (int m = 0; m < 16; ++m) { sc[m] = expf(sc[m] - mx); den += sc[m]; }
  float inv = 1.f / den;
#pragma unroll
  for (int m = 0; m < 16; ++m) sc[m] *= inv;
  float o[48];
#pragma unroll
  for (int d = 0; d < 48; ++d) o[d] = 0.f;
#pragma unroll
  for (int m = 0; m < 16; ++m) {
    const float* vr = Vl + m * 192 + h * 48;
    float a = sc[m];
#pragma unroll
    for (int d4 = 0; d4 < 12; ++d4) {
      float4 vv = *(const float4*)(vr + d4 * 4);
      o[d4 * 4 + 0] += a * vv.x; o[d4 * 4 + 1] += a * vv.y;
      o[d4 * 4 + 2] += a * vv.z; o[d4 * 4 + 3] += a * vv.w;
    }
  }
#pragma unroll
  for (int d2 = 0; d2 < 24; ++d2) {
    ushort_t t2[2] = { f2bu(o[d2 * 2]), f2bu(o[d2 * 2 + 1]) };
    *(unsigned*)(qp + d2 * 2) = *(unsigned*)t2;
  }
}

__device__ __forceinline__ void sofm_ep(f32x4* acc, const float* __restrict__ c_l,
                                        unsigned* __restrict__ hist, int lane) {
  const int c0 = lane & 15;
#pragma unroll
  for (int j = 0; j < 4; ++j) {
    float bv = -3.0e38f; int bi = 0;
#pragma unroll
    for (int t = 0; t < 4; ++t) {
      int gi = t * 16 + c0;
      float v = acc[t][j] - c_l[gi];
      bool take = (v > bv);
      bv = take ? v : bv; bi = take ? gi : bi;
    }
#pragma unroll
    for (int off = 1; off < 16; off <<= 1) {
      float ov = __shfl_xor(bv, off, 64);
      int   oi = __shfl_xor(bi, off, 64);
      bool take = (ov > bv) || (ov == bv && oi < bi);
      bv = take ? ov : bv; bi = take ? oi : bi;
    }
    if (c0 == 0) atomicAdd(&hist[bi], 1u);
  }
}

// ---------------- main fused kernel ----------------
__global__ __launch_bounds__(256, 3) void arn_main(
    const float* __restrict__ xv, const float* __restrict__ xa, const float* __restrict__ xt,
    const ushort_t* __restrict__ wsu, const float* __restrict__ kb, const float* __restrict__ vbnk,
    const float* __restrict__ ggn, unsigned* __restrict__ counts,
    const float* __restrict__ ebv, const float* __restrict__ egv, const float* __restrict__ ebbv,
    const float* __restrict__ eba, const float* __restrict__ ega, const float* __restrict__ ebba,
    const float* __restrict__ ebt, const float* __restrict__ egt, const float* __restrict__ ebbt,
    const float* __restrict__ fb, const float* __restrict__ fg, const float* __restrict__ fbb,
    const float* __restrict__ rbq, const float* __restrict__ rbo) {
  __shared__ __align__(16) ushort_t Abuf[64 * LDA];   // 25,600 B (activations, 64 rows x 192)
  __shared__ __align__(16) ushort_t Wbuf[64 * 200];   // 25,600 B (W chunk | K/V fp32 during attn)
  __shared__ float c_l[64];
  __shared__ unsigned hist[64];

  const int tid = threadIdx.x;
  const int lane = tid & 63, wave = tid >> 6;
  const int grow0 = blockIdx.x * 64;
  const int m = lane & 15, gq = lane >> 4;
  const int myrow = grow0 + wave * 16 + m;               // global row for A-frag loads
  ushort_t* Aw = Abuf + wave * 16 * LDA;                 // wave's 16-row A panel
  ushort_t* Arow0 = Abuf + (wave * 16 + 4 * gq) * LDA;   // epilogue row base (j adds rows)

  if (tid < 64) { hist[tid] = 0u; c_l[tid] = 0.5f * ggn[tid]; }

  f32x4 accF[12];
#pragma unroll
  for (int t = 0; t < 12; ++t) accF[t] = (f32x4){0.f, 0.f, 0.f, 0.f};

  // ---------- modality 0: vib (K=64, A direct from global) ----------
  {
    short8 af[2]; load_afrag<2>(xv, myrow, lane, af);
    f32x4 accE[12];
#pragma unroll
    for (int t = 0; t < 12; ++t) accE[t] = (f32x4){0.f, 0.f, 0.f, 0.f};
    for (int c = 0; c < 3; ++c) {
      stage_w(wsu + OFF_VIB, 64, 0, 64, c * 64, 72, Wbuf, tid);
      __syncthreads();
      mma_reg<4, 2>(af, Wbuf, 72, lane, accE + c * 4);
      __syncthreads();
    }
    ln_gelu_store(accE, ebv, egv, ebbv, Arow0, lane);
  }
  for (int c = 0; c < 3; ++c) {
    stage_w(wsu + OFF_FUS + 0 * 36864, 192, 0, 192, c * 64, 200, Wbuf, tid);
    __syncthreads();
    mma_lds<4, 6>(Aw, Wbuf, 200, lane, accF + c * 4);
    __syncthreads();
  }

  // ---------- modality 1: aco (K=256, staged in 2 k-halves) ----------
  {
    short8 af[8]; load_afrag<8>(xa, myrow, lane, af);
    f32x4 accE[12];
#pragma unroll
    for (int t = 0; t < 12; ++t) accE[t] = (f32x4){0.f, 0.f, 0.f, 0.f};
    for (int kh = 0; kh < 2; ++kh)
      for (int c = 0; c < 3; ++c) {
        stage_w(wsu + OFF_ACO, 256, kh * 128, 128, c * 64, 136, Wbuf, tid);
        __syncthreads();
        mma_reg<4, 4>(af + kh * 4, Wbuf, 136, lane, accE + c * 4);
        __syncthreads();
      }
    ln_gelu_store(accE, eba, ega, ebba, Arow0, lane);
  }
  for (int c = 0; c < 3; ++c) {
    stage_w(wsu + OFF_FUS + 1 * 36864, 192, 0, 192, c * 64, 200, Wbuf, tid);
    __syncthreads();
    mma_lds<4, 6>(Aw, Wbuf, 200, lane, accF + c * 4);
    __syncthreads();
  }

  // ---------- modality 2: tmp (K=128) ----------
  {
    short8 af[4]; load_afrag<4>(xt, myrow, lane, af);
    f32x4 accE[12];
#pragma unroll
    for (int t = 0; t < 12; ++t) accE[t] = (f32x4){0.f, 0.f, 0.f, 0.f};
    for (int c = 0; c < 3; ++c) {
      stage_w(wsu + OFF_TMP, 128, 0, 128, c * 64, 136, Wbuf, tid);
      __syncthreads();
      mma_reg<4, 4>(af, Wbuf, 136, lane, accE + c * 4);
      __syncthreads();
    }
    ln_gelu_store(accE, ebt, egt, ebbt, Arow0, lane);
  }
  for (int c = 0; c < 3; ++c) {
    stage_w(wsu + OFF_FUS + 2 * 36864, 192, 0, 192, c * 64, 200, Wbuf, tid);
    __syncthreads();
    mma_lds<4, 6>(Aw, Wbuf, 200, lane, accF + c * 4);
    __syncthreads();
  }
  // fusion epilogue: LN+GELU -> fused0 into Abuf (own rows)
  ln_gelu_store(accF, fb, fg, fbb, Arow0, lane);

  // ---------- 3 resonance layers ----------
  for (int i = 0; i < 3; ++i) {
    {
      f32x4 accQ[12];
#pragma unroll
      for (int t = 0; t < 12; ++t) accQ[t] = (f32x4){0.f, 0.f, 0.f, 0.f};
      for (int c = 0; c < 3; ++c) {
        stage_w(wsu + OFF_WQ + i * 36864, 192, 0, 192, c * 64, 200, Wbuf, tid);
        __syncthreads();
        mma_lds<4, 6>(Aw, Wbuf, 200, lane, accQ + c * 4);
        __syncthreads();
      }
      bias_store(accQ, rbq + i * 192, Arow0, lane);
    }
    // K/V (fp32) overlay into Wbuf
    stage_kv(kb + i * 3072, vbnk + i * 3072, (float*)Wbuf, tid);
    __syncthreads();
    attention((const float*)Wbuf, (const float*)Wbuf + 3072, Abuf, tid);
    __syncthreads();  // all waves done reading K/V before Wo staging
    {
      f32x4 accO[12];
#pragma unroll
      for (int t = 0; t < 12; ++t) accO[t] = (f32x4){0.f, 0.f, 0.f, 0.f};
      for (int c = 0; c < 3; ++c) {
        stage_w(wsu + OFF_WO + i * 36864, 192, 0, 192, c * 64, 200, Wbuf, tid);
        __syncthreads();
        mma_lds<4, 6>(Aw, Wbuf, 200, lane, accO + c * 4);
        __syncthreads();
      }
      bias_store(accO, rbo + i * 192, Arow0, lane);
    }
  }

  // ---------- SOFM: argmax_g (f.g - ||g||^2/2) -> histogram ----------
  stage_w(wsu + OFF_GRID, 192, 0, 192, 0, 200, Wbuf, tid);
  __syncthreads();
  {
    f32x4 accS[4];
#pragma unroll
    for (int t = 0; t < 4; ++t) accS[t] = (f32x4){0.f, 0.f, 0.f, 0.f};
    mma_lds<4, 6>(Aw, Wbuf, 200, lane, accS);
    sofm_ep(accS, c_l, hist, lane);
  }
  __syncthreads();
  if (tid < 64 && hist[tid]) atomicAdd(&counts[tid], hist[tid]);
}

// ---------------- finisher ----------------
__global__ void arn_finish(const unsigned* __restrict__ counts, const float* __restrict__ gr,
                           const float* __restrict__ ow, const float* __restrict__ ob,
                           float* __restrict__ out) {
  __shared__ float pooled[192];
  __shared__ float cf[64];
  int t = threadIdx.x;
  if (t < 64) cf[t] = (float)counts[t];
  __syncthreads();
  float s = 0.f;
  for (int g = 0; g < 64; ++g) s += cf[g] * gr[g * 192 + t];
  pooled[t] = s * (1.0f / (float)B_TOTAL);
  __syncthreads();
  if (t < 6) {
    float o = ob[t];
    for (int j = 0; j < 192; ++j) o += pooled[j] * ow[j * 6 + t];
    out[t] = (t == 1) ? fmaxf(o, 0.f) : 1.f / (1.f + expf(-o));
  }
}

// ---------------- launch ----------------
extern "C" void kernel_launch(void* const* d_in, const int* in_sizes, int n_in,
                              void* d_out, int out_size, void* d_ws, size_t ws_size,
                              hipStream_t stream) {
  (void)in_sizes; (void)n_in; (void)out_size; (void)ws_size;
  const float* xv   = (const float*)d_in[0];
  const float* xa   = (const float*)d_in[1];
  const float* xt   = (const float*)d_in[2];
  const float* ewv  = (const float*)d_in[3];
  const float* ebv  = (const float*)d_in[4];
  const float* egv  = (const float*)d_in[5];
  const float* ebbv = (const float*)d_in[6];
  const float* ewa  = (const float*)d_in[7];
  const float* eba  = (const float*)d_in[8];
  const float* ega  = (const float*)d_in[9];
  const float* ebba = (const float*)d_in[10];
  const float* ewt  = (const float*)d_in[11];
  const float* ebt  = (const float*)d_in[12];
  const float* egt  = (const float*)d_in[13];
  const float* ebbt = (const float*)d_in[14];
  const float* fw   = (const float*)d_in[15];
  const float* fb   = (const float*)d_in[16];
  const float* fg   = (const float*)d_in[17];
  const float* fbb  = (const float*)d_in[18];
  const float* rwq  = (const float*)d_in[19];
  const float* rwk  = (const float*)d_in[20];
  const float* rwv  = (const float*)d_in[21];
  const float* rwo  = (const float*)d_in[22];
  const float* rbq  = (const float*)d_in[23];
  const float* rbk  = (const float*)d_in[24];
  const float* rbv  = (const float*)d_in[25];
  const float* rbo  = (const float*)d_in[26];
  const float* rmem = (const float*)d_in[27];
  const float* grid = (const float*)d_in[28];
  const float* ow   = (const float*)d_in[29];
  const float* ob   = (const float*)d_in[30];

  ushort_t* wsu = (ushort_t*)d_ws;
  float* wsf = (float*)((char*)d_ws + F32_BYTE_OFF);
  float* kbank = wsf + F_KB;
  float* vbank = wsf + F_VB;
  float* ggn   = wsf + F_GGN;
  unsigned* cnt = (unsigned*)(wsf + F_CNT);

  prep_weights<<<dim3(256), dim3(256), 0, stream>>>(ewv, ewa, ewt, fw, rwq, rwo, grid, wsu);
  prep_kv<<<dim3(80), dim3(256), 0, stream>>>(rwk, rwv, rbk, rbv, rmem, grid, kbank, vbank, ggn, cnt);
  arn_main<<<dim3(2048), dim3(256), 0, stream>>>(xv, xa, xt, wsu, kbank, vbank, ggn, cnt,
      ebv, egv, ebbv, eba, ega, ebba, ebt, egt, ebbt, fb, fg, fbb, rbq, rbo);
  arn_finish<<<dim3(1), dim3(192), 0, stream>>>(cnt, grid, ow, ob, (float*)d_out);
}

// Round 3
// 439.724 us; speedup vs baseline: 2.5386x; 1.2215x over previous
//
#include <hip/hip_runtime.h>
#include <math.h>

typedef unsigned short ushort_t;
typedef __attribute__((ext_vector_type(8))) short short8;
typedef __attribute__((ext_vector_type(4))) float f32x4;

#define LDA 200
#define B_TOTAL 131072

// ws layout (ushort indices): weights, grid, then KV frags; fp32 region after.
#define OFF_VIB 0
#define OFF_ACO 12288
#define OFF_TMP 61440
#define OFF_FUS 86016
#define OFF_WQ 196608
#define OFF_WO 307200
#define OFF_GRID 417792
#define OFF_KV 430080              // 3 layers x 10240 ushorts (Kb 4096 + Vt 6144)
#define F32_BYTE_OFF 921600
#define F_GGN 0
#define F_CNT 64

__device__ __forceinline__ ushort_t f2bu(float f) {
  union { float f; unsigned u; } c; c.f = f;
  unsigned u = c.u;
  unsigned r = (u + 0x7fffu + ((u >> 16) & 1u)) >> 16;  // RTNE
  return (ushort_t)r;
}
__device__ __forceinline__ float fastrcp(float x) { return __builtin_amdgcn_rcpf(x); }
// tanh-form GELU (max |err| vs erf-GELU ~1e-3; well within bf16 noise here)
__device__ __forceinline__ float gelu_fast(float x) {
  float u = 0.7978845608f * x * (1.0f + 0.044715f * x * x);
  float E = exp2f(2.88539008f * u);          // e^{2u}; +inf ok
  float t = 1.0f - 2.0f * fastrcp(E + 1.0f); // tanh(u), NaN-free
  return 0.5f * x * (1.0f + t);
}

// ---------------- prep: weights -> bf16 transposed WT[n][k] ----------------
__global__ void prep_weights(const float* __restrict__ ev, const float* __restrict__ ea,
                             const float* __restrict__ et, const float* __restrict__ fw,
                             const float* __restrict__ rwq, const float* __restrict__ rwo,
                             const float* __restrict__ gr, ushort_t* __restrict__ ws) {
  int tid = blockIdx.x * blockDim.x + threadIdx.x;
  int nth = gridDim.x * blockDim.x;
  for (int i = tid; i < 12288; i += nth) { int n = i >> 6, k = i & 63;  ws[OFF_VIB + i] = f2bu(ev[k * 192 + n]); }
  for (int i = tid; i < 49152; i += nth) { int n = i >> 8, k = i & 255; ws[OFF_ACO + i] = f2bu(ea[k * 192 + n]); }
  for (int i = tid; i < 24576; i += nth) { int n = i >> 7, k = i & 127; ws[OFF_TMP + i] = f2bu(et[k * 192 + n]); }
  for (int i = tid; i < 110592; i += nth) {
    int c = i / 36864, r = i % 36864; int n = r / 192, k = r % 192;
    ws[OFF_FUS + i] = f2bu(fw[(c * 192 + k) * 192 + n]);
  }
  for (int i = tid; i < 110592; i += nth) {
    int l = i / 36864, r = i % 36864; int n = r / 192, k = r % 192;
    ws[OFF_WQ + i] = f2bu(rwq[l * 36864 + k * 192 + n]);
  }
  for (int i = tid; i < 110592; i += nth) {
    int l = i / 36864, r = i % 36864; int n = r / 192, k = r % 192;
    ws[OFF_WO + i] = f2bu(rwo[l * 36864 + k * 192 + n]);
  }
  for (int i = tid; i < 12288; i += nth) { ws[OFF_GRID + i] = f2bu(gr[i]); }
}

// -------- prep: K/V MFMA fragments (bf16), grid norms, zero counts --------
// Kb[i][h][s(16)][k(64)]: K[d=h*48+k] for k<48 else 0; chunk-XOR-swizzled.
// Vt[i][h][d(48)][k(32)]: V[slot=k][h*48+d] for k<16 else 0.
__global__ void prep_kv(const float* __restrict__ rwk, const float* __restrict__ rwv,
                        const float* __restrict__ rbk, const float* __restrict__ rbv,
                        const float* __restrict__ rmem, const float* __restrict__ gr,
                        ushort_t* __restrict__ kvf, float* __restrict__ ggn,
                        unsigned* __restrict__ cnt) {
  int tid = blockIdx.x * blockDim.x + threadIdx.x;
  int nth = gridDim.x * blockDim.x;
  for (int idx = tid; idx < 12288; idx += nth) {
    int i = idx >> 12, r = idx & 4095, h = r >> 10, s = (r >> 6) & 15, k = r & 63;
    float val = 0.f;
    if (k < 48) {
      int d = h * 48 + k;
      const float* w = rwk + i * 36864;
      const float* mm = rmem + i * 3072 + s * 192;
      float acc = rbk[i * 192 + d];
      for (int kk = 0; kk < 192; ++kk) acc += mm[kk] * w[kk * 192 + d];
      val = acc;
    }
    int c = k >> 3, kl = k & 7;
    kvf[i * 10240 + h * 1024 + s * 64 + (((c ^ (s & 7)) << 3) + kl)] = f2bu(val);
  }
  for (int idx = tid; idx < 18432; idx += nth) {
    int i = idx / 6144, r = idx % 6144, h = r / 1536, q = r % 1536, dd = q >> 5, k = q & 31;
    float val = 0.f;
    if (k < 16) {
      int d = h * 48 + dd;
      const float* w = rwv + i * 36864;
      const float* mm = rmem + i * 3072 + k * 192;
      float acc = rbv[i * 192 + d];
      for (int kk = 0; kk < 192; ++kk) acc += mm[kk] * w[kk * 192 + d];
      val = acc;
    }
    kvf[i * 10240 + 4096 + h * 1536 + dd * 32 + k] = f2bu(val);
  }
  for (int g = tid; g < 64; g += nth) {
    const float* gp = gr + g * 192;
    float s = 0.f;
    for (int k = 0; k < 192; ++k) s += gp[k] * gp[k];
    ggn[g] = s;
    cnt[g] = 0u;
  }
}

// ---------------- main kernel helpers ----------------
template<int KIT>
__device__ __forceinline__ void load_afrag(const float* __restrict__ x, int row, int lane, short8* af) {
  const int gq = lane >> 4;
  const float* p = x + (size_t)row * (KIT * 32) + gq * 8;
#pragma unroll
  for (int kk = 0; kk < KIT; ++kk) {
    float4 a = *(const float4*)(p + kk * 32);
    float4 b = *(const float4*)(p + kk * 32 + 4);
    short8 v;
    v[0] = (short)f2bu(a.x); v[1] = (short)f2bu(a.y); v[2] = (short)f2bu(a.z); v[3] = (short)f2bu(a.w);
    v[4] = (short)f2bu(b.x); v[5] = (short)f2bu(b.y); v[6] = (short)f2bu(b.z); v[7] = (short)f2bu(b.w);
    af[kk] = v;
  }
}

template<int NT, int KIT>
__device__ __forceinline__ void mma_reg(const short8* af, const ushort_t* W, int ldw, int lane, f32x4* acc) {
  const int m = lane & 15, gq = lane >> 4;
#pragma unroll
  for (int kk = 0; kk < KIT; ++kk) {
#pragma unroll
    for (int t = 0; t < NT; ++t) {
      short8 b = *(const short8*)(W + (t * 16 + m) * ldw + kk * 32 + gq * 8);
      acc[t] = __builtin_amdgcn_mfma_f32_16x16x32_bf16(af[kk], b, acc[t], 0, 0, 0);
    }
  }
}

template<int NT, int KIT>
__device__ __forceinline__ void mma_lds(const ushort_t* Aw, const ushort_t* W, int ldw, int lane, f32x4* acc) {
  const int m = lane & 15, gq = lane >> 4;
#pragma unroll
  for (int kk = 0; kk < KIT; ++kk) {
    short8 a = *(const short8*)(Aw + m * LDA + kk * 32 + gq * 8);
#pragma unroll
    for (int t = 0; t < NT; ++t) {
      short8 b = *(const short8*)(W + (t * 16 + m) * ldw + kk * 32 + gq * 8);
      acc[t] = __builtin_amdgcn_mfma_f32_16x16x32_bf16(a, b, acc[t], 0, 0, 0);
    }
  }
}

__device__ __forceinline__ void stage_w(const ushort_t* __restrict__ wt, int Kfull, int k0, int KC,
                                        int r0, int ldw, ushort_t* __restrict__ Wb, int tid) {
  const int per = KC >> 3;
  const int tot = per << 6;
  for (int idx = tid; idx < tot; idx += 256) {
    int r = idx / per, c = idx - r * per;
    short8 v = *(const short8*)(wt + (size_t)(r0 + r) * Kfull + k0 + c * 8);
    *(short8*)(Wb + r * ldw + c * 8) = v;
  }
}

__device__ __forceinline__ void stage_blob(const ushort_t* __restrict__ src, ushort_t* __restrict__ dst, int tid) {
  for (int idx = tid; idx < 1280; idx += 256)
    ((uint4*)dst)[idx] = ((const uint4*)src)[idx];  // 20480 B
}

__device__ __forceinline__ void ln_gelu_store(f32x4* acc, const float* __restrict__ bias,
                                              const float* __restrict__ gam, const float* __restrict__ bet,
                                              ushort_t* __restrict__ Arow0, int lane) {
  const int c0 = lane & 15;
#pragma unroll
  for (int t = 0; t < 12; ++t) {
    float bv = bias[t * 16 + c0];
#pragma unroll
    for (int j = 0; j < 4; ++j) acc[t][j] += bv;
  }
  float mean[4], rstd[4];
#pragma unroll
  for (int j = 0; j < 4; ++j) {
    float s = 0.f;
#pragma unroll
    for (int t = 0; t < 12; ++t) s += acc[t][j];
#pragma unroll
    for (int off = 1; off < 16; off <<= 1) s += __shfl_xor(s, off, 64);
    mean[j] = s * (1.0f / 192.0f);
    float qv = 0.f;
#pragma unroll
    for (int t = 0; t < 12; ++t) { float d = acc[t][j] - mean[j]; qv += d * d; }
#pragma unroll
    for (int off = 1; off < 16; off <<= 1) qv += __shfl_xor(qv, off, 64);
    rstd[j] = rsqrtf(qv * (1.0f / 192.0f) + 1e-5f);
  }
#pragma unroll
  for (int t = 0; t < 12; ++t) {
    int col = t * 16 + c0;
    float ga = gam[col], be = bet[col];
#pragma unroll
    for (int j = 0; j < 4; ++j) {
      float y = (acc[t][j] - mean[j]) * rstd[j] * ga + be;
      Arow0[j * LDA + col] = f2bu(gelu_fast(y));
    }
  }
}

__device__ __forceinline__ void bias_store(f32x4* acc, const float* __restrict__ bias,
                                           ushort_t* __restrict__ Arow0, int lane) {
  const int c0 = lane & 15;
#pragma unroll
  for (int t = 0; t < 12; ++t) {
    int col = t * 16 + c0;
    float bv = bias[col];
#pragma unroll
    for (int j = 0; j < 4; ++j)
      Arow0[j * LDA + col] = f2bu(acc[t][j] + bv);
  }
}

__device__ __forceinline__ void sofm_ep(f32x4* acc, const float* __restrict__ c_l,
                                        unsigned* __restrict__ hist, int lane) {
  const int c0 = lane & 15;
#pragma unroll
  for (int j = 0; j < 4; ++j) {
    float bv = -3.0e38f; int bi = 0;
#pragma unroll
    for (int t = 0; t < 4; ++t) {
      int gi = t * 16 + c0;
      float v = acc[t][j] - c_l[gi];
      bool take = (v > bv);
      bv = take ? v : bv; bi = take ? gi : bi;
    }
#pragma unroll
    for (int off = 1; off < 16; off <<= 1) {
      float ov = __shfl_xor(bv, off, 64);
      int   oi = __shfl_xor(bi, off, 64);
      bool take = (ov > bv) || (ov == bv && oi < bi);
      bv = take ? ov : bv; bi = take ? oi : bi;
    }
    if (c0 == 0) atomicAdd(&hist[bi], 1u);
  }
}

// ---------------- main fused kernel ----------------
__global__ __launch_bounds__(256, 3) void arn_main(
    const float* __restrict__ xv, const float* __restrict__ xa, const float* __restrict__ xt,
    const ushort_t* __restrict__ wsu, const ushort_t* __restrict__ kvf,
    const float* __restrict__ ggn, unsigned* __restrict__ counts,
    const float* __restrict__ ebv, const float* __restrict__ egv, const float* __restrict__ ebbv,
    const float* __restrict__ eba, const float* __restrict__ ega, const float* __restrict__ ebba,
    const float* __restrict__ ebt, const float* __restrict__ egt, const float* __restrict__ ebbt,
    const float* __restrict__ fb, const float* __restrict__ fg, const float* __restrict__ fbb,
    const float* __restrict__ rbq, const float* __restrict__ rbo) {
  __shared__ __align__(16) ushort_t Abuf[64 * LDA + 16];  // +16 slack for h=3 kk=1 over-read
  __shared__ __align__(16) ushort_t Wbuf[64 * 200];       // W chunk | KV frag blob + P scratch
  __shared__ float c_l[64];
  __shared__ unsigned hist[64];

  const int tid = threadIdx.x;
  const int lane = tid & 63, wave = tid >> 6;
  const int grow0 = blockIdx.x * 64;
  const int m = lane & 15, gq = lane >> 4;
  const int myrow = grow0 + wave * 16 + m;
  ushort_t* Aw = Abuf + wave * 16 * LDA;
  ushort_t* Arow0 = Abuf + (wave * 16 + 4 * gq) * LDA;

  if (tid < 64) { hist[tid] = 0u; c_l[tid] = 0.5f * ggn[tid]; }
  // One-time zero so never-written pad bytes are finite (NaN*0 = NaN in MFMA).
  for (int idx = tid; idx < 1600; idx += 256) ((uint4*)Wbuf)[idx] = (uint4){0u, 0u, 0u, 0u};
  for (int idx = tid; idx < 1602; idx += 256) ((uint4*)Abuf)[idx] = (uint4){0u, 0u, 0u, 0u};
  __syncthreads();

  f32x4 accF[12];
#pragma unroll
  for (int t = 0; t < 12; ++t) accF[t] = (f32x4){0.f, 0.f, 0.f, 0.f};

  // ---------- modality 0: vib (K=64, A direct from global) ----------
  {
    short8 af[2]; load_afrag<2>(xv, myrow, lane, af);
    f32x4 accE[12];
#pragma unroll
    for (int t = 0; t < 12; ++t) accE[t] = (f32x4){0.f, 0.f, 0.f, 0.f};
    for (int c = 0; c < 3; ++c) {
      stage_w(wsu + OFF_VIB, 64, 0, 64, c * 64, 72, Wbuf, tid);
      __syncthreads();
      mma_reg<4, 2>(af, Wbuf, 72, lane, accE + c * 4);
      __syncthreads();
    }
    ln_gelu_store(accE, ebv, egv, ebbv, Arow0, lane);
  }
  for (int c = 0; c < 3; ++c) {
    stage_w(wsu + OFF_FUS + 0 * 36864, 192, 0, 192, c * 64, 200, Wbuf, tid);
    __syncthreads();
    mma_lds<4, 6>(Aw, Wbuf, 200, lane, accF + c * 4);
    __syncthreads();
  }

  // ---------- modality 1: aco (K=256) ----------
  {
    short8 af[8]; load_afrag<8>(xa, myrow, lane, af);
    f32x4 accE[12];
#pragma unroll
    for (int t = 0; t < 12; ++t) accE[t] = (f32x4){0.f, 0.f, 0.f, 0.f};
    for (int kh = 0; kh < 2; ++kh)
      for (int c = 0; c < 3; ++c) {
        stage_w(wsu + OFF_ACO, 256, kh * 128, 128, c * 64, 136, Wbuf, tid);
        __syncthreads();
        mma_reg<4, 4>(af + kh * 4, Wbuf, 136, lane, accE + c * 4);
        __syncthreads();
      }
    ln_gelu_store(accE, eba, ega, ebba, Arow0, lane);
  }
  for (int c = 0; c < 3; ++c) {
    stage_w(wsu + OFF_FUS + 1 * 36864, 192, 0, 192, c * 64, 200, Wbuf, tid);
    __syncthreads();
    mma_lds<4, 6>(Aw, Wbuf, 200, lane, accF + c * 4);
    __syncthreads();
  }

  // ---------- modality 2: tmp (K=128) ----------
  {
    short8 af[4]; load_afrag<4>(xt, myrow, lane, af);
    f32x4 accE[12];
#pragma unroll
    for (int t = 0; t < 12; ++t) accE[t] = (f32x4){0.f, 0.f, 0.f, 0.f};
    for (int c = 0; c < 3; ++c) {
      stage_w(wsu + OFF_TMP, 128, 0, 128, c * 64, 136, Wbuf, tid);
      __syncthreads();
      mma_reg<4, 4>(af, Wbuf, 136, lane, accE + c * 4);
      __syncthreads();
    }
    ln_gelu_store(accE, ebt, egt, ebbt, Arow0, lane);
  }
  for (int c = 0; c < 3; ++c) {
    stage_w(wsu + OFF_FUS + 2 * 36864, 192, 0, 192, c * 64, 200, Wbuf, tid);
    __syncthreads();
    mma_lds<4, 6>(Aw, Wbuf, 200, lane, accF + c * 4);
    __syncthreads();
  }
  ln_gelu_store(accF, fb, fg, fbb, Arow0, lane);

  // ---------- 3 resonance layers ----------
  for (int i = 0; i < 3; ++i) {
    {
      f32x4 accQ[12];
#pragma unroll
      for (int t = 0; t < 12; ++t) accQ[t] = (f32x4){0.f, 0.f, 0.f, 0.f};
      for (int c = 0; c < 3; ++c) {
        stage_w(wsu + OFF_WQ + i * 36864, 192, 0, 192, c * 64, 200, Wbuf, tid);
        __syncthreads();
        mma_lds<4, 6>(Aw, Wbuf, 200, lane, accQ + c * 4);
        __syncthreads();
      }
      bias_store(accQ, rbq + i * 192, Arow0, lane);
    }
    // KV fragment blob -> Wbuf (Kb at 0, Vt at 4096; P scratch at 10240)
    stage_blob(kvf + i * 10240, Wbuf, tid);
    __syncthreads();
    // ---- MFMA attention (per-wave, own 16 rows; no cross-wave deps) ----
    {
      const ushort_t* Kb = Wbuf;
      const ushort_t* Vt = Wbuf + 4096;
      ushort_t* Pw = Wbuf + 10240 + wave * 512;  // [16 rows][32 slots] bf16
      const float scale = 0.144337567297406441f; // 1/sqrt(48)
#pragma unroll
      for (int h = 0; h < 4; ++h) {
        f32x4 s4 = (f32x4){0.f, 0.f, 0.f, 0.f};
#pragma unroll
        for (int kk = 0; kk < 2; ++kk) {
          short8 a = *(const short8*)(Aw + m * LDA + h * 48 + kk * 32 + gq * 8);
          short8 b = *(const short8*)(Kb + h * 1024 + m * 64 + (((kk * 4 + gq) ^ (m & 7)) << 3));
          s4 = __builtin_amdgcn_mfma_f32_16x16x32_bf16(a, b, s4, 0, 0, 0);
        }
#pragma unroll
        for (int j = 0; j < 4; ++j) {
          float v = s4[j] * scale;
          float mx = v;
#pragma unroll
          for (int off = 1; off < 16; off <<= 1) mx = fmaxf(mx, __shfl_xor(mx, off, 64));
          float e = exp2f((v - mx) * 1.44269504f);
          float sm = e;
#pragma unroll
          for (int off = 1; off < 16; off <<= 1) sm += __shfl_xor(sm, off, 64);
          Pw[(4 * gq + j) * 32 + m] = f2bu(e * fastrcp(sm));
        }
#pragma unroll
        for (int t = 0; t < 3; ++t) {
          short8 a = *(const short8*)(Pw + m * 32 + gq * 8);
          short8 b = *(const short8*)(Vt + h * 1536 + (t * 16 + m) * 32 + gq * 8);
          f32x4 o4 = __builtin_amdgcn_mfma_f32_16x16x32_bf16(a, b, (f32x4){0.f, 0.f, 0.f, 0.f}, 0, 0, 0);
#pragma unroll
          for (int j = 0; j < 4; ++j)
            Arow0[j * LDA + h * 48 + t * 16 + m] = f2bu(o4[j]);
        }
      }
    }
    __syncthreads();  // all PV reads done before Wo staging
    {
      f32x4 accO[12];
#pragma unroll
      for (int t = 0; t < 12; ++t) accO[t] = (f32x4){0.f, 0.f, 0.f, 0.f};
      for (int c = 0; c < 3; ++c) {
        stage_w(wsu + OFF_WO + i * 36864, 192, 0, 192, c * 64, 200, Wbuf, tid);
        __syncthreads();
        mma_lds<4, 6>(Aw, Wbuf, 200, lane, accO + c * 4);
        __syncthreads();
      }
      bias_store(accO, rbo + i * 192, Arow0, lane);
    }
  }

  // ---------- SOFM: argmax_g (f.g - ||g||^2/2) -> histogram ----------
  stage_w(wsu + OFF_GRID, 192, 0, 192, 0, 200, Wbuf, tid);
  __syncthreads();
  {
    f32x4 accS[4];
#pragma unroll
    for (int t = 0; t < 4; ++t) accS[t] = (f32x4){0.f, 0.f, 0.f, 0.f};
    mma_lds<4, 6>(Aw, Wbuf, 200, lane, accS);
    sofm_ep(accS, c_l, hist, lane);
  }
  __syncthreads();
  if (tid < 64 && hist[tid]) atomicAdd(&counts[tid], hist[tid]);
}

// ---------------- finisher ----------------
__global__ void arn_finish(const unsigned* __restrict__ counts, const float* __restrict__ gr,
                           const float* __restrict__ ow, const float* __restrict__ ob,
                           float* __restrict__ out) {
  __shared__ float pooled[192];
  __shared__ float cf[64];
  int t = threadIdx.x;
  if (t < 64) cf[t] = (float)counts[t];
  __syncthreads();
  float s = 0.f;
  for (int g = 0; g < 64; ++g) s += cf[g] * gr[g * 192 + t];
  pooled[t] = s * (1.0f / (float)B_TOTAL);
  __syncthreads();
  if (t < 6) {
    float o = ob[t];
    for (int j = 0; j < 192; ++j) o += pooled[j] * ow[j * 6 + t];
    out[t] = (t == 1) ? fmaxf(o, 0.f) : 1.f / (1.f + expf(-o));
  }
}

// ---------------- launch ----------------
extern "C" void kernel_launch(void* const* d_in, const int* in_sizes, int n_in,
                              void* d_out, int out_size, void* d_ws, size_t ws_size,
                              hipStream_t stream) {
  (void)in_sizes; (void)n_in; (void)out_size; (void)ws_size;
  const float* xv   = (const float*)d_in[0];
  const float* xa   = (const float*)d_in[1];
  const float* xt   = (const float*)d_in[2];
  const float* ewv  = (const float*)d_in[3];
  const float* ebv  = (const float*)d_in[4];
  const float* egv  = (const float*)d_in[5];
  const float* ebbv = (const float*)d_in[6];
  const float* ewa  = (const float*)d_in[7];
  const float* eba  = (const float*)d_in[8];
  const float* ega  = (const float*)d_in[9];
  const float* ebba = (const float*)d_in[10];
  const float* ewt  = (const float*)d_in[11];
  const float* ebt  = (const float*)d_in[12];
  const float* egt  = (const float*)d_in[13];
  const float* ebbt = (const float*)d_in[14];
  const float* fw   = (const float*)d_in[15];
  const float* fb   = (const float*)d_in[16];
  const float* fg   = (const float*)d_in[17];
  const float* fbb  = (const float*)d_in[18];
  const float* rwq  = (const float*)d_in[19];
  const float* rwk  = (const float*)d_in[20];
  const float* rwv  = (const float*)d_in[21];
  const float* rwo  = (const float*)d_in[22];
  const float* rbq  = (const float*)d_in[23];
  const float* rbk  = (const float*)d_in[24];
  const float* rbv  = (const float*)d_in[25];
  const float* rbo  = (const float*)d_in[26];
  const float* rmem = (const float*)d_in[27];
  const float* grid = (const float*)d_in[28];
  const float* ow   = (const float*)d_in[29];
  const float* ob   = (const float*)d_in[30];

  ushort_t* wsu = (ushort_t*)d_ws;
  ushort_t* kvf = wsu + OFF_KV;
  float* wsf = (float*)((char*)d_ws + F32_BYTE_OFF);
  float* ggn = wsf + F_GGN;
  unsigned* cnt = (unsigned*)(wsf + F_CNT);

  prep_weights<<<dim3(256), dim3(256), 0, stream>>>(ewv, ewa, ewt, fw, rwq, rwo, grid, wsu);
  prep_kv<<<dim3(120), dim3(256), 0, stream>>>(rwk, rwv, rbk, rbv, rmem, grid, kvf, ggn, cnt);
  arn_main<<<dim3(2048), dim3(256), 0, stream>>>(xv, xa, xt, wsu, kvf, ggn, cnt,
      ebv, egv, ebbv, eba, ega, ebba, ebt, egt, ebbt, fb, fg, fbb, rbq, rbo);
  arn_finish<<<dim3(1), dim3(192), 0, stream>>>(cnt, grid, ow, ob, (float*)d_out);
}